// Round 4
// baseline (3466.264 us; speedup 1.0000x reference)
//
#include <hip/hip_runtime.h>

#define NN 100000
#define NE 1600000
#define NB 2
#define CH 8
#define HID 16
#define NTILES 98   // ceil(NN/1024)

typedef unsigned int uint;

__device__ __forceinline__ float soft_clamp(float x) {
    float y = x * 1e-6f;
    return x * (1.0f - 0.33333333f * y * y);  // 1e6*tanh(x/1e6), |x| small
}
__device__ __forceinline__ float fast_tanh(float x) {
    float ax = fabsf(x);
    float t = __expf(-2.0f * ax);
    float r = (1.0f - t) / (1.0f + t);
    return copysignf(r, x);
}
__device__ __forceinline__ void load8(const float* __restrict__ p, float* x) {
    float4 a = ((const float4*)p)[0];
    float4 b = ((const float4*)p)[1];
    x[0]=a.x; x[1]=a.y; x[2]=a.z; x[3]=a.w; x[4]=b.x; x[5]=b.y; x[6]=b.z; x[7]=b.w;
}
__device__ __forceinline__ void store8(float* __restrict__ p, const float* x) {
    ((float4*)p)[0] = make_float4(x[0],x[1],x[2],x[3]);
    ((float4*)p)[1] = make_float4(x[4],x[5],x[6],x[7]);
}
__device__ __forceinline__ void f4w(float* p, float4 v){ p[0]=v.x; p[1]=v.y; p[2]=v.z; p[3]=v.w; }

__device__ __forceinline__ uint bfu(float x) {  // f32 -> bf16 bits (RNE)
    uint u = __float_as_uint(x);
    return (u + 0x7fffu + ((u >> 16) & 1u)) >> 16;
}
__device__ __forceinline__ float ubf(uint u) { return __uint_as_float(u << 16); }

__device__ __forceinline__ ushort f2h(float x) {
    _Float16 h = (_Float16)x;
    union { _Float16 h; ushort u; } c; c.h = h; return c.u;
}
__device__ __forceinline__ float h2f(uint u) {
    union { ushort u; _Float16 h; } c; c.u = (ushort)u; return (float)c.h;
}
__device__ __forceinline__ float dot8h(uint4 a, uint4 b) {
    const uint* pa = &a.x; const uint* pb = &b.x;
    float s = 0.0f;
#pragma unroll
    for (int i = 0; i < 4; i++) {
        s += h2f(pa[i] & 0xffffu) * h2f(pb[i] & 0xffffu);
        s += h2f(pa[i] >> 16)     * h2f(pb[i] >> 16);
    }
    return s;
}

// ---------------- att MLP per node + packed layouts ----------------
// attS[n]: 64B = {b0: a_key 8f16 | a_query 8f16, b1: same}
// attT[n]: 64B = {b0: b_key 8f16 | b_query 8f16, b1: same}
// nodesP[n]: 64B = {b0: 8 f32, b1: 8 f32}
__global__ void __launch_bounds__(256)
att_pack_kernel(const float* __restrict__ nodes,
                const float* __restrict__ w1, const float* __restrict__ b1,
                const float* __restrict__ w2, const float* __restrict__ b2,
                uint4* __restrict__ attS, uint4* __restrict__ attT,
                float4* __restrict__ nodesP) {
    __shared__ float sw1[CH*HID], sb1[HID], sw2[HID*32], sb2[32];
    int tid = threadIdx.x;
    for (int i = tid; i < CH*HID; i += 256) sw1[i] = w1[i];
    for (int i = tid; i < HID; i += 256) sb1[i] = b1[i];
    for (int i = tid; i < HID*32; i += 256) sw2[i] = w2[i];
    for (int i = tid; i < 32; i += 256) sb2[i] = b2[i];
    __syncthreads();
    int n = blockIdx.x * 256 + tid;
    if (n >= NN) return;
    int b = blockIdx.y;
    size_t base = (size_t)b * NN + n;

    float x[CH];
    load8(nodes + base * CH, x);
    nodesP[(size_t)n*4 + b*2]     = make_float4(x[0],x[1],x[2],x[3]);
    nodesP[(size_t)n*4 + b*2 + 1] = make_float4(x[4],x[5],x[6],x[7]);

    float h[HID];
#pragma unroll
    for (int j = 0; j < HID; j++) {
        float acc = sb1[j];
#pragma unroll
        for (int i = 0; i < CH; i++) acc += x[i] * sw1[i*HID + j];
        h[j] = fast_tanh(acc);
    }
    float o[32];
#pragma unroll
    for (int k = 0; k < 32; k++) {
        float acc = sb2[k];
#pragma unroll
        for (int j = 0; j < HID; j++) acc += h[j] * sw2[j*32 + k];
        o[k] = acc;
    }
    uint4 ak, aq, bk, bq;
    ak.x=f2h(o[0]) |(f2h(o[1]) <<16); ak.y=f2h(o[2]) |(f2h(o[3]) <<16);
    ak.z=f2h(o[4]) |(f2h(o[5]) <<16); ak.w=f2h(o[6]) |(f2h(o[7]) <<16);
    aq.x=f2h(o[8]) |(f2h(o[9]) <<16); aq.y=f2h(o[10])|(f2h(o[11])<<16);
    aq.z=f2h(o[12])|(f2h(o[13])<<16); aq.w=f2h(o[14])|(f2h(o[15])<<16);
    bk.x=f2h(o[16])|(f2h(o[17])<<16); bk.y=f2h(o[18])|(f2h(o[19])<<16);
    bk.z=f2h(o[20])|(f2h(o[21])<<16); bk.w=f2h(o[22])|(f2h(o[23])<<16);
    bq.x=f2h(o[24])|(f2h(o[25])<<16); bq.y=f2h(o[26])|(f2h(o[27])<<16);
    bq.z=f2h(o[28])|(f2h(o[29])<<16); bq.w=f2h(o[30])|(f2h(o[31])<<16);
    attS[(size_t)n*4 + b*2]     = ak;
    attS[(size_t)n*4 + b*2 + 1] = aq;
    attT[(size_t)n*4 + b*2]     = bk;
    attT[(size_t)n*4 + b*2 + 1] = bq;
}

// ---------------- CSR build ----------------
__global__ void __launch_bounds__(256)
hist_kernel(const int* __restrict__ src, const int* __restrict__ tgt,
            int* __restrict__ cntA, int* __restrict__ cntB) {
    int e = blockIdx.x * 256 + threadIdx.x;
    if (e >= NE) return;
    atomicAdd(&cntA[src[e]], 1);
    atomicAdd(&cntB[tgt[e]], 1);
}

__global__ void __launch_bounds__(256)
scan_part_kernel(const int* __restrict__ cnt, int* __restrict__ part) {
    int y = blockIdx.y;
    const int* c = cnt + (size_t)y * NN;
    __shared__ int s[256];
    int t = threadIdx.x, bx = blockIdx.x;
    int base = bx * 1024 + t * 4;
    int sum = 0;
#pragma unroll
    for (int k = 0; k < 4; k++) { int i = base + k; sum += (i < NN) ? c[i] : 0; }
    s[t] = sum; __syncthreads();
    for (int off = 128; off > 0; off >>= 1) { if (t < off) s[t] += s[t + off]; __syncthreads(); }
    if (t == 0) part[y * 256 + bx] = s[0];
}

__global__ void __launch_bounds__(256)
scan_top_kernel(int* __restrict__ part, int* __restrict__ rowA, int* __restrict__ rowB) {
    int y = blockIdx.y; int t = threadIdx.x;
    __shared__ int s[256];
    int v = (t < NTILES) ? part[y * 256 + t] : 0;
    s[t] = v; __syncthreads();
    for (int off = 1; off < 256; off <<= 1) {
        int x = (t >= off) ? s[t - off] : 0;
        __syncthreads();
        s[t] += x;
        __syncthreads();
    }
    part[y * 256 + t] = t ? s[t - 1] : 0;
    if (t == 0) (y ? rowB : rowA)[NN] = NE;
}

__global__ void __launch_bounds__(256)
scan_down_kernel(const int* __restrict__ cnt, const int* __restrict__ part,
                 int* __restrict__ rowA, int* __restrict__ rowB,
                 int* __restrict__ curA, int* __restrict__ curB) {
    int y = blockIdx.y;
    const int* c = cnt + (size_t)y * NN;
    int* row = y ? rowB : rowA;
    int* cur = y ? curB : curA;
    __shared__ int s[256];
    int t = threadIdx.x, bx = blockIdx.x;
    int base = bx * 1024 + t * 4;
    int v[4]; int tsum = 0;
#pragma unroll
    for (int k = 0; k < 4; k++) { int i = base + k; v[k] = (i < NN) ? c[i] : 0; tsum += v[k]; }
    s[t] = tsum; __syncthreads();
    for (int off = 1; off < 256; off <<= 1) {
        int x = (t >= off) ? s[t - off] : 0;
        __syncthreads();
        s[t] += x;
        __syncthreads();
    }
    int run = part[y * 256 + bx] + s[t] - tsum;
#pragma unroll
    for (int k = 0; k < 4; k++) {
        int i = base + k;
        if (i < NN) { row[i] = run; cur[i] = run; }
        run += v[k];
    }
}

// scatter: record each edge's CSR slot (rank) per side
__global__ void __launch_bounds__(256)
scatter_kernel(const int* __restrict__ src, const int* __restrict__ tgt,
               int* __restrict__ curA, int* __restrict__ curB,
               int* __restrict__ rankA, int* __restrict__ rankB) {
    int e = blockIdx.x * 256 + threadIdx.x;
    if (e >= NE) return;
    rankA[e] = atomicAdd(&curA[src[e]], 1);
    rankB[e] = atomicAdd(&curB[tgt[e]], 1);
}

// ---------------- edge: both batches per thread, payload written to CSR slots ----------------
// recA slot (64B): [b0: logit f32, m_a 8bf16, 12B pad][b1: same]; recB with logit_b, m_b.
__global__ void __launch_bounds__(256, 4)
edge_kernel(const float4* __restrict__ nodesP, const float* __restrict__ edges,
            const int* __restrict__ src, const int* __restrict__ tgt,
            const int* __restrict__ rankA, const int* __restrict__ rankB,
            const float* __restrict__ w1, const float* __restrict__ b1,
            const float* __restrict__ w2, const float* __restrict__ b2,
            const uint4* __restrict__ attS, const uint4* __restrict__ attT,
            float* __restrict__ out_edges,
            uint4* __restrict__ recA, uint4* __restrict__ recB) {
    __shared__ float sw1[24*HID], sb1[HID], sw2[HID*24], sb2[24];
    int tid = threadIdx.x;
    for (int i = tid; i < 24*HID; i += 256) sw1[i] = w1[i];
    for (int i = tid; i < HID; i += 256) sb1[i] = b1[i];
    for (int i = tid; i < HID*24; i += 256) sw2[i] = w2[i];
    for (int i = tid; i < 24; i += 256) sb2[i] = b2[i];
    __syncthreads();
    int e = blockIdx.x * 256 + tid;
    if (e >= NE) return;
    int s = src[e], t = tgt[e];
    int pA = rankA[e], pB = rankB[e];
    const float scale = 0.35355339059327373f;

#pragma unroll
    for (int b = 0; b < NB; b++) {
        // per-batch re-gather: both batches share a 64B line -> 2nd iter hits L1/L2
        float in[24];
        f4w(in,      nodesP[(size_t)s*4 + b*2]);
        f4w(in + 4,  nodesP[(size_t)s*4 + b*2 + 1]);
        f4w(in + 8,  nodesP[(size_t)t*4 + b*2]);
        f4w(in + 12, nodesP[(size_t)t*4 + b*2 + 1]);
        load8(edges + ((size_t)b*NE + e)*CH, in + 16);

        uint4 ak = attS[(size_t)s*4 + b*2], aq = attS[(size_t)s*4 + b*2 + 1];
        uint4 bk = attT[(size_t)t*4 + b*2], bq = attT[(size_t)t*4 + b*2 + 1];
        float la = scale * dot8h(aq, bk);   // a_query(s)·b_key(t)
        float lb = scale * dot8h(bq, ak);   // b_query(t)·a_key(s)

        float h[HID];
#pragma unroll
        for (int j = 0; j < HID; j++) {
            float acc = sb1[j];
#pragma unroll
            for (int i = 0; i < 24; i++) acc += in[i] * sw1[i*HID + j];
            h[j] = fast_tanh(acc);
        }
        float m[24];
#pragma unroll
        for (int k = 0; k < 24; k++) {
            float acc = sb2[k];
#pragma unroll
            for (int j = 0; j < HID; j++) acc += h[j] * sw2[j*24 + k];
            m[k] = acc;
        }

        float eo[CH];
#pragma unroll
        for (int c = 0; c < CH; c++) eo[c] = soft_clamp(in[16+c] + m[16+c]);
        store8(out_edges + ((size_t)b*NE + e)*CH, eo);

        uint4 r0, r1;
        r0.x = __float_as_uint(la);
        r0.y = bfu(m[0]) | (bfu(m[1]) << 16);
        r0.z = bfu(m[2]) | (bfu(m[3]) << 16);
        r0.w = bfu(m[4]) | (bfu(m[5]) << 16);
        r1.x = bfu(m[6]) | (bfu(m[7]) << 16);
        r1.y = r1.z = r1.w = 0u;
        recA[(size_t)pA*4 + b*2]     = r0;
        recA[(size_t)pA*4 + b*2 + 1] = r1;
        r0.x = __float_as_uint(lb);
        r0.y = bfu(m[8])  | (bfu(m[9])  << 16);
        r0.z = bfu(m[10]) | (bfu(m[11]) << 16);
        r0.w = bfu(m[12]) | (bfu(m[13]) << 16);
        r1.x = bfu(m[14]) | (bfu(m[15]) << 16);
        recB[(size_t)pB*4 + b*2]     = r0;
        recB[(size_t)pB*4 + b*2 + 1] = r1;
    }
}

// ---------------- node: sequential CSR slots, both batches ----------------
__device__ __forceinline__ void aggregate(int beg, int end, const uint4* __restrict__ rec,
                                          float* __restrict__ o0, float* __restrict__ o1) {
    float mx0 = -1e30f, den0 = 0.0f, num0[CH];
    float mx1 = -1e30f, den1 = 0.0f, num1[CH];
#pragma unroll
    for (int c = 0; c < CH; c++) { num0[c] = 0.0f; num1[c] = 0.0f; }
    for (int i = beg; i < end; ++i) {
        const uint4* P = rec + (size_t)i*4;
        uint4 q0 = P[0], q1 = P[1], q2 = P[2], q3 = P[3];
        {   // batch 0
            float l = __uint_as_float(q0.x);
            float nm = fmaxf(mx0, l);
            float r = __expf(mx0 - nm), w = __expf(l - nm);
            mx0 = nm; den0 = den0 * r + w;
            float mm[CH];
            mm[0]=ubf(q0.y&0xffffu); mm[1]=ubf(q0.y>>16);
            mm[2]=ubf(q0.z&0xffffu); mm[3]=ubf(q0.z>>16);
            mm[4]=ubf(q0.w&0xffffu); mm[5]=ubf(q0.w>>16);
            mm[6]=ubf(q1.x&0xffffu); mm[7]=ubf(q1.x>>16);
#pragma unroll
            for (int c = 0; c < CH; c++) num0[c] = num0[c] * r + w * mm[c];
        }
        {   // batch 1
            float l = __uint_as_float(q2.x);
            float nm = fmaxf(mx1, l);
            float r = __expf(mx1 - nm), w = __expf(l - nm);
            mx1 = nm; den1 = den1 * r + w;
            float mm[CH];
            mm[0]=ubf(q2.y&0xffffu); mm[1]=ubf(q2.y>>16);
            mm[2]=ubf(q2.z&0xffffu); mm[3]=ubf(q2.z>>16);
            mm[4]=ubf(q2.w&0xffffu); mm[5]=ubf(q2.w>>16);
            mm[6]=ubf(q3.x&0xffffu); mm[7]=ubf(q3.x>>16);
#pragma unroll
            for (int c = 0; c < CH; c++) num1[c] = num1[c] * r + w * mm[c];
        }
    }
    float i0 = 1.0f / (den0 + 1e-10f), i1 = 1.0f / (den1 + 1e-10f);
#pragma unroll
    for (int c = 0; c < CH; c++) { o0[c] = num0[c] * i0; o1[c] = num1[c] * i1; }
}

__device__ __forceinline__ void upd_mlp(const float* __restrict__ in,
                                        const float* __restrict__ sw1, const float* __restrict__ sb1,
                                        const float* __restrict__ sw2, const float* __restrict__ sb2,
                                        float* __restrict__ no) {
    float h[HID];
#pragma unroll
    for (int j = 0; j < HID; j++) {
        float acc = sb1[j];
#pragma unroll
        for (int i = 0; i < 24; i++) acc += in[i] * sw1[i*HID + j];
        h[j] = fast_tanh(acc);
    }
#pragma unroll
    for (int k = 0; k < CH; k++) {
        float acc = sb2[k];
#pragma unroll
        for (int j = 0; j < HID; j++) acc += h[j] * sw2[j*CH + k];
        no[k] = soft_clamp(in[k] + acc);
    }
}

__global__ void __launch_bounds__(256, 4)
node_kernel(const float4* __restrict__ nodesP,
            const int* __restrict__ rowA, const int* __restrict__ rowB,
            const uint4* __restrict__ recA, const uint4* __restrict__ recB,
            const float* __restrict__ w1, const float* __restrict__ b1,
            const float* __restrict__ w2, const float* __restrict__ b2,
            float* __restrict__ out_nodes) {
    __shared__ float sw1[24*HID], sb1[HID], sw2[HID*CH], sb2[CH];
    int tid = threadIdx.x;
    for (int i = tid; i < 24*HID; i += 256) sw1[i] = w1[i];
    for (int i = tid; i < HID; i += 256) sb1[i] = b1[i];
    for (int i = tid; i < HID*CH; i += 256) sw2[i] = w2[i];
    for (int i = tid; i < CH; i += 256) sb2[i] = b2[i];
    __syncthreads();
    int n = blockIdx.x * 256 + tid;
    if (n >= NN) return;

    float in0[24], in1[24];
    float4 np0 = nodesP[(size_t)n*4+0], np1 = nodesP[(size_t)n*4+1];
    float4 np2 = nodesP[(size_t)n*4+2], np3 = nodesP[(size_t)n*4+3];
    f4w(in0, np0); f4w(in0+4, np1);
    f4w(in1, np2); f4w(in1+4, np3);

    aggregate(rowA[n], rowA[n+1], recA, in0 + 8,  in1 + 8);
    aggregate(rowB[n], rowB[n+1], recB, in0 + 16, in1 + 16);

    float no0[CH], no1[CH];
    upd_mlp(in0, sw1, sb1, sw2, sb2, no0);
    upd_mlp(in1, sw1, sb1, sw2, sb2, no1);
    store8(out_nodes + (size_t)n*CH, no0);
    store8(out_nodes + (size_t)NN*CH + (size_t)n*CH, no1);
}

extern "C" void kernel_launch(void* const* d_in, const int* in_sizes, int n_in,
                              void* d_out, int out_size, void* d_ws, size_t ws_size,
                              hipStream_t stream) {
    const float* nodes  = (const float*)d_in[0];
    const float* edges  = (const float*)d_in[1];
    const float* msg_w1 = (const float*)d_in[2];
    const float* msg_b1 = (const float*)d_in[3];
    const float* msg_w2 = (const float*)d_in[4];
    const float* msg_b2 = (const float*)d_in[5];
    const float* att_w1 = (const float*)d_in[6];
    const float* att_b1 = (const float*)d_in[7];
    const float* att_w2 = (const float*)d_in[8];
    const float* att_b2 = (const float*)d_in[9];
    const float* upd_w1 = (const float*)d_in[10];
    const float* upd_b1 = (const float*)d_in[11];
    const float* upd_w2 = (const float*)d_in[12];
    const float* upd_b2 = (const float*)d_in[13];
    const int*   sources = (const int*)d_in[14];
    const int*   targets = (const int*)d_in[15];

    float* out       = (float*)d_out;
    float* out_nodes = out;
    float* out_edges = out + (size_t)NB * NN * CH;

    char* wp = (char*)d_ws;
    size_t off = 0;
    auto take = [&](size_t bytes) -> char* {
        char* p = wp + off;
        off = (off + bytes + 255) & ~(size_t)255;
        return p;
    };
    uint4*  attS   = (uint4*)take((size_t)NN * 64);
    uint4*  attT   = (uint4*)take((size_t)NN * 64);
    float4* nodesP = (float4*)take((size_t)NN * 64);
    int*    cnt    = (int*)take((size_t)2 * NN * 4);
    int*    rowA   = (int*)take((size_t)(NN + 1) * 4);
    int*    rowB   = (int*)take((size_t)(NN + 1) * 4);
    int*    curA   = (int*)take((size_t)NN * 4);
    int*    curB   = (int*)take((size_t)NN * 4);
    int*    part   = (int*)take((size_t)2 * 256 * 4);
    int*    rankA  = (int*)take((size_t)NE * 4);
    int*    rankB  = (int*)take((size_t)NE * 4);
    uint4*  recA   = (uint4*)take((size_t)NE * 64);
    uint4*  recB   = (uint4*)take((size_t)NE * 64);
    int* cntA = cnt, *cntB = cnt + NN;

    dim3 gn((NN + 255) / 256, NB);
    dim3 gn1((NN + 255) / 256);
    dim3 ge1((NE + 255) / 256);
    dim3 gs(NTILES, 2);
    dim3 gt(1, 2);

    hipMemsetAsync(cnt, 0, (size_t)2 * NN * 4, stream);
    att_pack_kernel<<<gn, 256, 0, stream>>>(nodes, att_w1, att_b1, att_w2, att_b2,
                                            attS, attT, nodesP);
    hist_kernel<<<ge1, 256, 0, stream>>>(sources, targets, cntA, cntB);
    scan_part_kernel<<<gs, 256, 0, stream>>>(cnt, part);
    scan_top_kernel<<<gt, 256, 0, stream>>>(part, rowA, rowB);
    scan_down_kernel<<<gs, 256, 0, stream>>>(cnt, part, rowA, rowB, curA, curB);
    scatter_kernel<<<ge1, 256, 0, stream>>>(sources, targets, curA, curB, rankA, rankB);
    edge_kernel<<<ge1, 256, 0, stream>>>(nodesP, edges, sources, targets, rankA, rankB,
                                         msg_w1, msg_b1, msg_w2, msg_b2,
                                         attS, attT, out_edges, recA, recB);
    node_kernel<<<gn1, 256, 0, stream>>>(nodesP, rowA, rowB, recA, recB,
                                         upd_w1, upd_b1, upd_w2, upd_b2, out_nodes);
}

// Round 5
// 1479.904 us; speedup vs baseline: 2.3422x; 2.3422x over previous
//
#include <hip/hip_runtime.h>

#define NN 100000
#define NE 1600000
#define NB 2
#define CH 8
#define HID 16
#define NTILES 98   // ceil(NN/1024)

typedef unsigned int uint;

__device__ __forceinline__ float soft_clamp(float x) {
    float y = x * 1e-6f;
    return x * (1.0f - 0.33333333f * y * y);  // 1e6*tanh(x/1e6), |x| small
}
__device__ __forceinline__ float fast_tanh(float x) {
    float ax = fabsf(x);
    float t = __expf(-2.0f * ax);
    float r = (1.0f - t) / (1.0f + t);
    return copysignf(r, x);
}
__device__ __forceinline__ void load8(const float* __restrict__ p, float* x) {
    float4 a = ((const float4*)p)[0];
    float4 b = ((const float4*)p)[1];
    x[0]=a.x; x[1]=a.y; x[2]=a.z; x[3]=a.w; x[4]=b.x; x[5]=b.y; x[6]=b.z; x[7]=b.w;
}
__device__ __forceinline__ void store8(float* __restrict__ p, const float* x) {
    ((float4*)p)[0] = make_float4(x[0],x[1],x[2],x[3]);
    ((float4*)p)[1] = make_float4(x[4],x[5],x[6],x[7]);
}
__device__ __forceinline__ void f4w(float* p, float4 v){ p[0]=v.x; p[1]=v.y; p[2]=v.z; p[3]=v.w; }

__device__ __forceinline__ uint bfu(float x) {  // f32 -> bf16 bits (RNE)
    uint u = __float_as_uint(x);
    return (u + 0x7fffu + ((u >> 16) & 1u)) >> 16;
}
__device__ __forceinline__ float ubf(uint u) { return __uint_as_float(u << 16); }

__device__ __forceinline__ ushort f2h(float x) {
    _Float16 h = (_Float16)x;
    union { _Float16 h; ushort u; } c; c.h = h; return c.u;
}
__device__ __forceinline__ float h2f(uint u) {
    union { ushort u; _Float16 h; } c; c.u = (ushort)u; return (float)c.h;
}
__device__ __forceinline__ float dot8h(uint4 a, uint4 b) {
    const uint* pa = &a.x; const uint* pb = &b.x;
    float s = 0.0f;
#pragma unroll
    for (int i = 0; i < 4; i++) {
        s += h2f(pa[i] & 0xffffu) * h2f(pb[i] & 0xffffu);
        s += h2f(pa[i] >> 16)     * h2f(pb[i] >> 16);
    }
    return s;
}

// ---------------- att MLP per node + packed layouts ----------------
// attS[n]: 64B = {b0: a_key 8f16 | a_query 8f16, b1: same}
// attT[n]: 64B = {b0: b_key 8f16 | b_query 8f16, b1: same}
// nodesP[n]: 64B = {b0: 8 f32, b1: 8 f32}
__global__ void __launch_bounds__(256)
att_pack_kernel(const float* __restrict__ nodes,
                const float* __restrict__ w1, const float* __restrict__ b1,
                const float* __restrict__ w2, const float* __restrict__ b2,
                uint4* __restrict__ attS, uint4* __restrict__ attT,
                float4* __restrict__ nodesP) {
    __shared__ float sw1[CH*HID], sb1[HID], sw2[HID*32], sb2[32];
    int tid = threadIdx.x;
    for (int i = tid; i < CH*HID; i += 256) sw1[i] = w1[i];
    for (int i = tid; i < HID; i += 256) sb1[i] = b1[i];
    for (int i = tid; i < HID*32; i += 256) sw2[i] = w2[i];
    for (int i = tid; i < 32; i += 256) sb2[i] = b2[i];
    __syncthreads();
    int n = blockIdx.x * 256 + tid;
    if (n >= NN) return;
    int b = blockIdx.y;
    size_t base = (size_t)b * NN + n;

    float x[CH];
    load8(nodes + base * CH, x);
    nodesP[(size_t)n*4 + b*2]     = make_float4(x[0],x[1],x[2],x[3]);
    nodesP[(size_t)n*4 + b*2 + 1] = make_float4(x[4],x[5],x[6],x[7]);

    float h[HID];
#pragma unroll
    for (int j = 0; j < HID; j++) {
        float acc = sb1[j];
#pragma unroll
        for (int i = 0; i < CH; i++) acc += x[i] * sw1[i*HID + j];
        h[j] = fast_tanh(acc);
    }
    float o[32];
#pragma unroll
    for (int k = 0; k < 32; k++) {
        float acc = sb2[k];
#pragma unroll
        for (int j = 0; j < HID; j++) acc += h[j] * sw2[j*32 + k];
        o[k] = acc;
    }
    uint4 ak, aq, bk, bq;
    ak.x=f2h(o[0]) |(f2h(o[1]) <<16); ak.y=f2h(o[2]) |(f2h(o[3]) <<16);
    ak.z=f2h(o[4]) |(f2h(o[5]) <<16); ak.w=f2h(o[6]) |(f2h(o[7]) <<16);
    aq.x=f2h(o[8]) |(f2h(o[9]) <<16); aq.y=f2h(o[10])|(f2h(o[11])<<16);
    aq.z=f2h(o[12])|(f2h(o[13])<<16); aq.w=f2h(o[14])|(f2h(o[15])<<16);
    bk.x=f2h(o[16])|(f2h(o[17])<<16); bk.y=f2h(o[18])|(f2h(o[19])<<16);
    bk.z=f2h(o[20])|(f2h(o[21])<<16); bk.w=f2h(o[22])|(f2h(o[23])<<16);
    bq.x=f2h(o[24])|(f2h(o[25])<<16); bq.y=f2h(o[26])|(f2h(o[27])<<16);
    bq.z=f2h(o[28])|(f2h(o[29])<<16); bq.w=f2h(o[30])|(f2h(o[31])<<16);
    attS[(size_t)n*4 + b*2]     = ak;
    attS[(size_t)n*4 + b*2 + 1] = aq;
    attT[(size_t)n*4 + b*2]     = bk;
    attT[(size_t)n*4 + b*2 + 1] = bq;
}

// ---------------- CSR build ----------------
__global__ void __launch_bounds__(256)
hist_kernel(const int* __restrict__ src, const int* __restrict__ tgt,
            int* __restrict__ cntA, int* __restrict__ cntB) {
    int e = blockIdx.x * 256 + threadIdx.x;
    if (e >= NE) return;
    atomicAdd(&cntA[src[e]], 1);
    atomicAdd(&cntB[tgt[e]], 1);
}

__global__ void __launch_bounds__(256)
scan_part_kernel(const int* __restrict__ cnt, int* __restrict__ part) {
    int y = blockIdx.y;
    const int* c = cnt + (size_t)y * NN;
    __shared__ int s[256];
    int t = threadIdx.x, bx = blockIdx.x;
    int base = bx * 1024 + t * 4;
    int sum = 0;
#pragma unroll
    for (int k = 0; k < 4; k++) { int i = base + k; sum += (i < NN) ? c[i] : 0; }
    s[t] = sum; __syncthreads();
    for (int off = 128; off > 0; off >>= 1) { if (t < off) s[t] += s[t + off]; __syncthreads(); }
    if (t == 0) part[y * 256 + bx] = s[0];
}

__global__ void __launch_bounds__(256)
scan_top_kernel(int* __restrict__ part, int* __restrict__ rowA, int* __restrict__ rowB) {
    int y = blockIdx.y; int t = threadIdx.x;
    __shared__ int s[256];
    int v = (t < NTILES) ? part[y * 256 + t] : 0;
    s[t] = v; __syncthreads();
    for (int off = 1; off < 256; off <<= 1) {
        int x = (t >= off) ? s[t - off] : 0;
        __syncthreads();
        s[t] += x;
        __syncthreads();
    }
    part[y * 256 + t] = t ? s[t - 1] : 0;
    if (t == 0) (y ? rowB : rowA)[NN] = NE;
}

__global__ void __launch_bounds__(256)
scan_down_kernel(const int* __restrict__ cnt, const int* __restrict__ part,
                 int* __restrict__ rowA, int* __restrict__ rowB,
                 int* __restrict__ curA, int* __restrict__ curB) {
    int y = blockIdx.y;
    const int* c = cnt + (size_t)y * NN;
    int* row = y ? rowB : rowA;
    int* cur = y ? curB : curA;
    __shared__ int s[256];
    int t = threadIdx.x, bx = blockIdx.x;
    int base = bx * 1024 + t * 4;
    int v[4]; int tsum = 0;
#pragma unroll
    for (int k = 0; k < 4; k++) { int i = base + k; v[k] = (i < NN) ? c[i] : 0; tsum += v[k]; }
    s[t] = tsum; __syncthreads();
    for (int off = 1; off < 256; off <<= 1) {
        int x = (t >= off) ? s[t - off] : 0;
        __syncthreads();
        s[t] += x;
        __syncthreads();
    }
    int run = part[y * 256 + bx] + s[t] - tsum;
#pragma unroll
    for (int k = 0; k < 4; k++) {
        int i = base + k;
        if (i < NN) { row[i] = run; cur[i] = run; }
        run += v[k];
    }
}

__global__ void __launch_bounds__(256)
scatter_kernel(const int* __restrict__ src, const int* __restrict__ tgt,
               int* __restrict__ curA, int* __restrict__ curB,
               int* __restrict__ eidA, int* __restrict__ eidB) {
    int e = blockIdx.x * 256 + threadIdx.x;
    if (e >= NE) return;
    int p1 = atomicAdd(&curA[src[e]], 1); eidA[p1] = e;
    int p2 = atomicAdd(&curB[tgt[e]], 1); eidB[p2] = e;
}

// ---------------- edge: 1 thread = 1 edge, both batches; sequential 64B records ----------------
// recA[e] 64B: q0={la_b0, ma_b0[0:6)}, q1={ma_b0[6:8), la_b1, ma_b1[0:4)}, q2={ma_b1[4:8), 0,0}, q3=0
__global__ void __launch_bounds__(256)
edge_kernel(const float4* __restrict__ nodesP, const float* __restrict__ edges,
            const int* __restrict__ src, const int* __restrict__ tgt,
            const float* __restrict__ w1, const float* __restrict__ b1,
            const float* __restrict__ w2, const float* __restrict__ b2,
            const uint4* __restrict__ attS, const uint4* __restrict__ attT,
            float* __restrict__ out_edges,
            uint4* __restrict__ recA, uint4* __restrict__ recB) {
    __shared__ float sw1[24*HID], sb1[HID], sw2[HID*24], sb2[24];
    int tid = threadIdx.x;
    for (int i = tid; i < 24*HID; i += 256) sw1[i] = w1[i];
    for (int i = tid; i < HID; i += 256) sb1[i] = b1[i];
    for (int i = tid; i < HID*24; i += 256) sw2[i] = w2[i];
    for (int i = tid; i < 24; i += 256) sb2[i] = b2[i];
    __syncthreads();
    int e = blockIdx.x * 256 + tid;
    if (e >= NE) return;
    int s = src[e], t = tgt[e];
    const float scale = 0.35355339059327373f;

    // logits for both batches up front (att regs die early)
    float la[NB], lb[NB];
    {
        uint4 as0 = attS[(size_t)s*4+0], as1 = attS[(size_t)s*4+1];
        uint4 as2 = attS[(size_t)s*4+2], as3 = attS[(size_t)s*4+3];
        uint4 at0 = attT[(size_t)t*4+0], at1 = attT[(size_t)t*4+1];
        uint4 at2 = attT[(size_t)t*4+2], at3 = attT[(size_t)t*4+3];
        la[0] = scale * dot8h(as1, at0);  // a_query(s)·b_key(t)
        lb[0] = scale * dot8h(at1, as0);  // b_query(t)·a_key(s)
        la[1] = scale * dot8h(as3, at2);
        lb[1] = scale * dot8h(at3, as2);
    }

    uint pa[NB][4], pb[NB][4];
#pragma unroll
    for (int b = 0; b < NB; b++) {
        float in[24];
        f4w(in,      nodesP[(size_t)s*4 + b*2]);
        f4w(in + 4,  nodesP[(size_t)s*4 + b*2 + 1]);
        f4w(in + 8,  nodesP[(size_t)t*4 + b*2]);
        f4w(in + 12, nodesP[(size_t)t*4 + b*2 + 1]);
        load8(edges + ((size_t)b*NE + e)*CH, in + 16);

        float h[HID];
#pragma unroll
        for (int j = 0; j < HID; j++) {
            float acc = sb1[j];
#pragma unroll
            for (int i = 0; i < 24; i++) acc += in[i] * sw1[i*HID + j];
            h[j] = fast_tanh(acc);
        }
        float m[24];
#pragma unroll
        for (int k = 0; k < 24; k++) {
            float acc = sb2[k];
#pragma unroll
            for (int j = 0; j < HID; j++) acc += h[j] * sw2[j*24 + k];
            m[k] = acc;
        }

        float eo[CH];
#pragma unroll
        for (int c = 0; c < CH; c++) eo[c] = soft_clamp(in[16+c] + m[16+c]);
        store8(out_edges + ((size_t)b*NE + e)*CH, eo);

#pragma unroll
        for (int k = 0; k < 4; k++) pa[b][k] = bfu(m[2*k])   | (bfu(m[2*k+1])   << 16);
#pragma unroll
        for (int k = 0; k < 4; k++) pb[b][k] = bfu(m[8+2*k]) | (bfu(m[8+2*k+1]) << 16);
    }

    // full-line writes, back-to-back
    uint4 q0, q1, q2, q3;
    q3 = make_uint4(0u, 0u, 0u, 0u);
    q0 = make_uint4(__float_as_uint(la[0]), pa[0][0], pa[0][1], pa[0][2]);
    q1 = make_uint4(pa[0][3], __float_as_uint(la[1]), pa[1][0], pa[1][1]);
    q2 = make_uint4(pa[1][2], pa[1][3], 0u, 0u);
    recA[(size_t)e*4+0] = q0; recA[(size_t)e*4+1] = q1;
    recA[(size_t)e*4+2] = q2; recA[(size_t)e*4+3] = q3;
    q0 = make_uint4(__float_as_uint(lb[0]), pb[0][0], pb[0][1], pb[0][2]);
    q1 = make_uint4(pb[0][3], __float_as_uint(lb[1]), pb[1][0], pb[1][1]);
    q2 = make_uint4(pb[1][2], pb[1][3], 0u, 0u);
    recB[(size_t)e*4+0] = q0; recB[(size_t)e*4+1] = q1;
    recB[(size_t)e*4+2] = q2; recB[(size_t)e*4+3] = q3;
}

// ---------------- node: eid walk, one 64B record per appearance ----------------
__device__ __forceinline__ void aggregate(int beg, int end, const int* __restrict__ eid,
                                          const uint4* __restrict__ rec,
                                          float* __restrict__ o0, float* __restrict__ o1) {
    float mx0 = -1e30f, den0 = 0.0f, num0[CH];
    float mx1 = -1e30f, den1 = 0.0f, num1[CH];
#pragma unroll
    for (int c = 0; c < CH; c++) { num0[c] = 0.0f; num1[c] = 0.0f; }
    for (int i = beg; i < end; ++i) {
        int e = eid[i];
        const uint4* P = rec + (size_t)e*4;
        uint4 q0 = P[0], q1 = P[1], q2 = P[2];
        {   // batch 0: l=q0.x, m = q0.y,q0.z,q0.w,q1.x
            float l = __uint_as_float(q0.x);
            float nm = fmaxf(mx0, l);
            float r = __expf(mx0 - nm), w = __expf(l - nm);
            mx0 = nm; den0 = den0 * r + w;
            float mm[CH];
            mm[0]=ubf(q0.y&0xffffu); mm[1]=ubf(q0.y>>16);
            mm[2]=ubf(q0.z&0xffffu); mm[3]=ubf(q0.z>>16);
            mm[4]=ubf(q0.w&0xffffu); mm[5]=ubf(q0.w>>16);
            mm[6]=ubf(q1.x&0xffffu); mm[7]=ubf(q1.x>>16);
#pragma unroll
            for (int c = 0; c < CH; c++) num0[c] = num0[c] * r + w * mm[c];
        }
        {   // batch 1: l=q1.y, m = q1.z,q1.w,q2.x,q2.y
            float l = __uint_as_float(q1.y);
            float nm = fmaxf(mx1, l);
            float r = __expf(mx1 - nm), w = __expf(l - nm);
            mx1 = nm; den1 = den1 * r + w;
            float mm[CH];
            mm[0]=ubf(q1.z&0xffffu); mm[1]=ubf(q1.z>>16);
            mm[2]=ubf(q1.w&0xffffu); mm[3]=ubf(q1.w>>16);
            mm[4]=ubf(q2.x&0xffffu); mm[5]=ubf(q2.x>>16);
            mm[6]=ubf(q2.y&0xffffu); mm[7]=ubf(q2.y>>16);
#pragma unroll
            for (int c = 0; c < CH; c++) num1[c] = num1[c] * r + w * mm[c];
        }
    }
    float i0 = 1.0f / (den0 + 1e-10f), i1 = 1.0f / (den1 + 1e-10f);
#pragma unroll
    for (int c = 0; c < CH; c++) { o0[c] = num0[c] * i0; o1[c] = num1[c] * i1; }
}

__device__ __forceinline__ void upd_mlp(const float* __restrict__ in,
                                        const float* __restrict__ sw1, const float* __restrict__ sb1,
                                        const float* __restrict__ sw2, const float* __restrict__ sb2,
                                        float* __restrict__ no) {
    float h[HID];
#pragma unroll
    for (int j = 0; j < HID; j++) {
        float acc = sb1[j];
#pragma unroll
        for (int i = 0; i < 24; i++) acc += in[i] * sw1[i*HID + j];
        h[j] = fast_tanh(acc);
    }
#pragma unroll
    for (int k = 0; k < CH; k++) {
        float acc = sb2[k];
#pragma unroll
        for (int j = 0; j < HID; j++) acc += h[j] * sw2[j*CH + k];
        no[k] = soft_clamp(in[k] + acc);
    }
}

__global__ void __launch_bounds__(256)
node_kernel(const float4* __restrict__ nodesP,
            const int* __restrict__ rowA, const int* __restrict__ rowB,
            const int* __restrict__ eidA, const int* __restrict__ eidB,
            const uint4* __restrict__ recA, const uint4* __restrict__ recB,
            const float* __restrict__ w1, const float* __restrict__ b1,
            const float* __restrict__ w2, const float* __restrict__ b2,
            float* __restrict__ out_nodes) {
    __shared__ float sw1[24*HID], sb1[HID], sw2[HID*CH], sb2[CH];
    int tid = threadIdx.x;
    for (int i = tid; i < 24*HID; i += 256) sw1[i] = w1[i];
    for (int i = tid; i < HID; i += 256) sb1[i] = b1[i];
    for (int i = tid; i < HID*CH; i += 256) sw2[i] = w2[i];
    for (int i = tid; i < CH; i += 256) sb2[i] = b2[i];
    __syncthreads();
    int n = blockIdx.x * 256 + tid;
    if (n >= NN) return;

    float in0[24], in1[24];
    float4 np0 = nodesP[(size_t)n*4+0], np1 = nodesP[(size_t)n*4+1];
    float4 np2 = nodesP[(size_t)n*4+2], np3 = nodesP[(size_t)n*4+3];
    f4w(in0, np0); f4w(in0+4, np1);
    f4w(in1, np2); f4w(in1+4, np3);

    aggregate(rowA[n], rowA[n+1], eidA, recA, in0 + 8,  in1 + 8);
    aggregate(rowB[n], rowB[n+1], eidB, recB, in0 + 16, in1 + 16);

    float no0[CH], no1[CH];
    upd_mlp(in0, sw1, sb1, sw2, sb2, no0);
    upd_mlp(in1, sw1, sb1, sw2, sb2, no1);
    store8(out_nodes + (size_t)n*CH, no0);
    store8(out_nodes + (size_t)NN*CH + (size_t)n*CH, no1);
}

extern "C" void kernel_launch(void* const* d_in, const int* in_sizes, int n_in,
                              void* d_out, int out_size, void* d_ws, size_t ws_size,
                              hipStream_t stream) {
    const float* nodes  = (const float*)d_in[0];
    const float* edges  = (const float*)d_in[1];
    const float* msg_w1 = (const float*)d_in[2];
    const float* msg_b1 = (const float*)d_in[3];
    const float* msg_w2 = (const float*)d_in[4];
    const float* msg_b2 = (const float*)d_in[5];
    const float* att_w1 = (const float*)d_in[6];
    const float* att_b1 = (const float*)d_in[7];
    const float* att_w2 = (const float*)d_in[8];
    const float* att_b2 = (const float*)d_in[9];
    const float* upd_w1 = (const float*)d_in[10];
    const float* upd_b1 = (const float*)d_in[11];
    const float* upd_w2 = (const float*)d_in[12];
    const float* upd_b2 = (const float*)d_in[13];
    const int*   sources = (const int*)d_in[14];
    const int*   targets = (const int*)d_in[15];

    float* out       = (float*)d_out;
    float* out_nodes = out;
    float* out_edges = out + (size_t)NB * NN * CH;

    char* wp = (char*)d_ws;
    size_t off = 0;
    auto take = [&](size_t bytes) -> char* {
        char* p = wp + off;
        off = (off + bytes + 255) & ~(size_t)255;
        return p;
    };
    uint4*  attS   = (uint4*)take((size_t)NN * 64);
    uint4*  attT   = (uint4*)take((size_t)NN * 64);
    float4* nodesP = (float4*)take((size_t)NN * 64);
    int*    cnt    = (int*)take((size_t)2 * NN * 4);
    int*    rowA   = (int*)take((size_t)(NN + 1) * 4);
    int*    rowB   = (int*)take((size_t)(NN + 1) * 4);
    int*    curA   = (int*)take((size_t)NN * 4);
    int*    curB   = (int*)take((size_t)NN * 4);
    int*    part   = (int*)take((size_t)2 * 256 * 4);
    int*    eidA   = (int*)take((size_t)NE * 4);
    int*    eidB   = (int*)take((size_t)NE * 4);
    uint4*  recA   = (uint4*)take((size_t)NE * 64);
    uint4*  recB   = (uint4*)take((size_t)NE * 64);
    int* cntA = cnt, *cntB = cnt + NN;

    dim3 gn((NN + 255) / 256, NB);
    dim3 gn1((NN + 255) / 256);
    dim3 ge1((NE + 255) / 256);
    dim3 gs(NTILES, 2);
    dim3 gt(1, 2);

    hipMemsetAsync(cnt, 0, (size_t)2 * NN * 4, stream);
    att_pack_kernel<<<gn, 256, 0, stream>>>(nodes, att_w1, att_b1, att_w2, att_b2,
                                            attS, attT, nodesP);
    hist_kernel<<<ge1, 256, 0, stream>>>(sources, targets, cntA, cntB);
    scan_part_kernel<<<gs, 256, 0, stream>>>(cnt, part);
    scan_top_kernel<<<gt, 256, 0, stream>>>(part, rowA, rowB);
    scan_down_kernel<<<gs, 256, 0, stream>>>(cnt, part, rowA, rowB, curA, curB);
    scatter_kernel<<<ge1, 256, 0, stream>>>(sources, targets, curA, curB, eidA, eidB);
    edge_kernel<<<ge1, 256, 0, stream>>>(nodesP, edges, sources, targets,
                                         msg_w1, msg_b1, msg_w2, msg_b2,
                                         attS, attT, out_edges, recA, recB);
    node_kernel<<<gn1, 256, 0, stream>>>(nodesP, rowA, rowB, eidA, eidB, recA, recB,
                                         upd_w1, upd_b1, upd_w2, upd_b2, out_nodes);
}